// Round 1
// baseline (230.568 us; speedup 1.0000x reference)
//
#include <hip/hip_runtime.h>
#include <math.h>

#define NHEAD 8

// ---------------- K0a: q[j] = (query . W_in[j,:] + b_in[j]) * scale, j in [0,D) ----------------
__global__ void k_qproj(const float* __restrict__ query, const float* __restrict__ W_in,
                        const float* __restrict__ b_in, float* __restrict__ q_ws,
                        int D, float scale) {
    int j = blockIdx.x * blockDim.x + threadIdx.x;
    if (j >= D) return;
    const float4* wq = reinterpret_cast<const float4*>(W_in + (size_t)j * D);
    const float4* qv = reinterpret_cast<const float4*>(query);
    float acc = 0.f;
    for (int i = 0; i < D / 4; ++i) {
        float4 w = wq[i], q = qv[i];
        acc += w.x * q.x + w.y * q.y + w.z * q.z + w.w * q.w;
    }
    q_ws[j] = (acc + b_in[j]) * scale;
}

// ---------------- K0b: wsc[h*D+i] = sum_d q[h*dh+d] * W_k[(h*dh+d), i] ----------------
__global__ void k_wscore(const float* __restrict__ q_ws, const float* __restrict__ W_in,
                         float* __restrict__ wsc, int D, int dh) {
    int idx = blockIdx.x * blockDim.x + threadIdx.x; // h*D + i
    if (idx >= NHEAD * D) return;
    int h = idx / D, i = idx - h * D;
    const float* Wk = W_in + (size_t)D * D; // rows [D, 2D)
    float acc = 0.f;
    for (int d = 0; d < dh; ++d)
        acc += q_ws[h * dh + d] * Wk[(size_t)(h * dh + d) * D + i];
    wsc[idx] = acc;
}

// ---------------- K1: segment boundaries from sorted batch ids ----------------
__global__ void k_bounds(const int* __restrict__ batch, int* __restrict__ seg_start,
                         int* __restrict__ seg_end, int N) {
    int n = blockIdx.x * blockDim.x + threadIdx.x;
    if (n >= N) return;
    int b = batch[n];
    if (n == 0 || batch[n - 1] != b) seg_start[b] = n;
    if (n == N - 1 || batch[n + 1] != b) seg_end[b] = n + 1;
}

// ---------------- K2: scores[n,h] = x[n,:] . wsc[h,:]   (D==512, wave per row) ----------------
__global__ void __launch_bounds__(256) k_scores(const float* __restrict__ x,
                                                const float* __restrict__ wsc,
                                                float* __restrict__ scores, int N) {
    const int t = threadIdx.x, lane = t & 63, wid = t >> 6;
    const int gw = blockIdx.x * 4 + wid;
    float4 w0[NHEAD], w1[NHEAD];
#pragma unroll
    for (int h = 0; h < NHEAD; ++h) {
        w0[h] = *reinterpret_cast<const float4*>(wsc + h * 512 + lane * 8);
        w1[h] = *reinterpret_cast<const float4*>(wsc + h * 512 + lane * 8 + 4);
    }
    const int base = gw * 16;
    for (int r = 0; r < 16; ++r) {
        int row = base + r;
        if (row >= N) return;
        const float* xr = x + (size_t)row * 512 + lane * 8;
        float4 xa = *reinterpret_cast<const float4*>(xr);
        float4 xb = *reinterpret_cast<const float4*>(xr + 4);
        float acc[NHEAD];
#pragma unroll
        for (int h = 0; h < NHEAD; ++h) {
            acc[h] = xa.x * w0[h].x + xa.y * w0[h].y + xa.z * w0[h].z + xa.w * w0[h].w +
                     xb.x * w1[h].x + xb.y * w1[h].y + xb.z * w1[h].z + xb.w * w1[h].w;
        }
#pragma unroll
        for (int h = 0; h < NHEAD; ++h) {
#pragma unroll
            for (int off = 1; off < 64; off <<= 1)
                acc[h] += __shfl_xor(acc[h], off, 64);
        }
        if (lane == 0) {
            float4 s0 = {acc[0], acc[1], acc[2], acc[3]};
            float4 s1 = {acc[4], acc[5], acc[6], acc[7]};
            float4* sp = reinterpret_cast<float4*>(scores + (size_t)row * 8);
            sp[0] = s0;
            sp[1] = s1;
        }
    }
}

// ---------------- K3: per-graph segment softmax + xp[b,h,i] = sum_n p[n,h]*x[n,i] ----------------
// one block (256 threads) per graph; D==512, H==8
__global__ void __launch_bounds__(256) k_softmax_xp(const float* __restrict__ x,
                                                    const float* __restrict__ scores,
                                                    const int* __restrict__ seg_start,
                                                    const int* __restrict__ seg_end,
                                                    float* __restrict__ xp) {
    const int b = blockIdx.x, t = threadIdx.x;
    __shared__ float part[256];
    __shared__ float mx[NHEAD], rden[NHEAD];
    __shared__ float plds[64][NHEAD];
    const int s0 = seg_start[b], s1 = seg_end[b];
    const int h = t & 7, nl = t >> 3;

    // per-head max
    float m = -1e30f;
    for (int n = s0 + nl; n < s1; n += 32) m = fmaxf(m, scores[(size_t)n * 8 + h]);
    part[t] = m;
    __syncthreads();
    if (t < NHEAD) {
        float mm = -1e30f;
        for (int g = 0; g < 32; ++g) mm = fmaxf(mm, part[g * 8 + t]);
        mx[t] = mm;
    }
    __syncthreads();
    // per-head sum of exp
    float s = 0.f;
    for (int n = s0 + nl; n < s1; n += 32) s += __expf(scores[(size_t)n * 8 + h] - mx[h]);
    part[t] = s;
    __syncthreads();
    if (t < NHEAD) {
        float ss = 0.f;
        for (int g = 0; g < 32; ++g) ss += part[g * 8 + t];
        rden[t] = 1.f / ss;
    }
    __syncthreads();

    // weighted accumulation: thread owns cols 2t, 2t+1 for all 8 heads
    float a00 = 0, a01 = 0, a10 = 0, a11 = 0, a20 = 0, a21 = 0, a30 = 0, a31 = 0;
    float a40 = 0, a41 = 0, a50 = 0, a51 = 0, a60 = 0, a61 = 0, a70 = 0, a71 = 0;

    for (int base = s0; base < s1; base += 64) {
#pragma unroll
        for (int rep = 0; rep < 2; ++rep) {
            int e = t + rep * 256;
            int c = e >> 3, hh = e & 7;
            int n = base + c;
            if (n < s1) plds[c][hh] = __expf(scores[(size_t)n * 8 + hh] - mx[hh]) * rden[hh];
        }
        __syncthreads();
        int lim = min(64, s1 - base);
#pragma unroll 4
        for (int c = 0; c < lim; ++c) {
            float2 xv = *reinterpret_cast<const float2*>(x + (size_t)(base + c) * 512 + t * 2);
            float4 p0 = *reinterpret_cast<const float4*>(&plds[c][0]);
            float4 p1 = *reinterpret_cast<const float4*>(&plds[c][4]);
            a00 += p0.x * xv.x; a01 += p0.x * xv.y;
            a10 += p0.y * xv.x; a11 += p0.y * xv.y;
            a20 += p0.z * xv.x; a21 += p0.z * xv.y;
            a30 += p0.w * xv.x; a31 += p0.w * xv.y;
            a40 += p1.x * xv.x; a41 += p1.x * xv.y;
            a50 += p1.y * xv.x; a51 += p1.y * xv.y;
            a60 += p1.z * xv.x; a61 += p1.z * xv.y;
            a70 += p1.w * xv.x; a71 += p1.w * xv.y;
        }
        __syncthreads();
    }
    float* xpb = xp + (size_t)b * 8 * 512 + t * 2;
    float2 o;
    o.x = a00; o.y = a01; *reinterpret_cast<float2*>(xpb + 0 * 512) = o;
    o.x = a10; o.y = a11; *reinterpret_cast<float2*>(xpb + 1 * 512) = o;
    o.x = a20; o.y = a21; *reinterpret_cast<float2*>(xpb + 2 * 512) = o;
    o.x = a30; o.y = a31; *reinterpret_cast<float2*>(xpb + 3 * 512) = o;
    o.x = a40; o.y = a41; *reinterpret_cast<float2*>(xpb + 4 * 512) = o;
    o.x = a50; o.y = a51; *reinterpret_cast<float2*>(xpb + 5 * 512) = o;
    o.x = a60; o.y = a61; *reinterpret_cast<float2*>(xpb + 6 * 512) = o;
    o.x = a70; o.y = a71; *reinterpret_cast<float2*>(xpb + 7 * 512) = o;
}

// ---------------- tiled f32 GEMM: C[m,n] = sum_k A[m,k]*B[n,k] + bias[n] ----------------
// 32x32 tile, 256 threads, 2x2 per thread. blockIdx.z applies offsets (for per-head batching).
__global__ void __launch_bounds__(256) k_gemm_tn(const float* __restrict__ A, int lda, int zA,
                                                 const float* __restrict__ Bm, int ldb, int zB,
                                                 const float* __restrict__ bias, int zBias,
                                                 float* __restrict__ C, int ldc, int zC, int K) {
    __shared__ float As[32][33];
    __shared__ float Bs[32][33];
    const int z = blockIdx.z;
    A += (size_t)z * zA;
    Bm += (size_t)z * zB;
    bias += (size_t)z * zBias;
    C += (size_t)z * zC;
    const int m0 = blockIdx.x * 32, n0 = blockIdx.y * 32;
    const int t = threadIdx.x;
    const int lr = t >> 3, lk = (t & 7) * 4;
    const int ty = t >> 4, tx = t & 15;
    float c00 = 0, c01 = 0, c10 = 0, c11 = 0;
    for (int k0 = 0; k0 < K; k0 += 32) {
        float4 a = *reinterpret_cast<const float4*>(A + (size_t)(m0 + lr) * lda + k0 + lk);
        float4 bb = *reinterpret_cast<const float4*>(Bm + (size_t)(n0 + lr) * ldb + k0 + lk);
        As[lr][lk + 0] = a.x; As[lr][lk + 1] = a.y; As[lr][lk + 2] = a.z; As[lr][lk + 3] = a.w;
        Bs[lr][lk + 0] = bb.x; Bs[lr][lk + 1] = bb.y; Bs[lr][lk + 2] = bb.z; Bs[lr][lk + 3] = bb.w;
        __syncthreads();
#pragma unroll
        for (int kk = 0; kk < 32; ++kk) {
            float a0 = As[ty * 2][kk], a1 = As[ty * 2 + 1][kk];
            float b0 = Bs[tx * 2][kk], b1 = Bs[tx * 2 + 1][kk];
            c00 += a0 * b0;
            c01 += a0 * b1;
            c10 += a1 * b0;
            c11 += a1 * b1;
        }
        __syncthreads();
    }
    const int r0 = m0 + ty * 2, cx = n0 + tx * 2;
    float bv0 = bias[cx], bv1 = bias[cx + 1];
    C[(size_t)r0 * ldc + cx] = c00 + bv0;
    C[(size_t)r0 * ldc + cx + 1] = c01 + bv1;
    C[(size_t)(r0 + 1) * ldc + cx] = c10 + bv0;
    C[(size_t)(r0 + 1) * ldc + cx + 1] = c11 + bv1;
}

extern "C" void kernel_launch(void* const* d_in, const int* in_sizes, int n_in,
                              void* d_out, int out_size, void* d_ws, size_t ws_size,
                              hipStream_t stream) {
    const float* x     = (const float*)d_in[0];
    const int*   batch = (const int*)d_in[1];
    // d_in[2] = num_graphs scalar (derived from out_size instead)
    const float* query = (const float*)d_in[3];
    const float* W_in  = (const float*)d_in[4];
    const float* b_in  = (const float*)d_in[5];
    const float* W_out = (const float*)d_in[6];
    const float* b_out = (const float*)d_in[7];
    float* out = (float*)d_out;

    const int D = in_sizes[3];         // 512
    const int N = in_sizes[0] / D;     // 131072
    const int B = out_size / D;        // 512 graphs
    const int dh = D / NHEAD;          // 64
    const float scale = 1.0f / sqrtf((float)dh);

    // workspace carve (floats)
    float* wsf     = (float*)d_ws;
    float* q_ws    = wsf;                                // D
    float* wsc     = wsf + 512;                          // H*D
    float* scores  = wsf + 512 + NHEAD * 512;            // N*H
    float* xp      = scores + (size_t)N * NHEAD;         // B*H*D
    float* pooled  = xp + (size_t)B * NHEAD * 512;       // B*D
    int*   seg_start = (int*)(pooled + (size_t)B * 512); // B
    int*   seg_end   = seg_start + B;                    // B

    // K0: q projection + score-weight folding
    k_qproj<<<(D + 255) / 256, 256, 0, stream>>>(query, W_in, b_in, q_ws, D, scale);
    k_wscore<<<(NHEAD * D + 255) / 256, 256, 0, stream>>>(q_ws, W_in, wsc, D, dh);

    // K1: segment bounds
    k_bounds<<<(N + 255) / 256, 256, 0, stream>>>(batch, seg_start, seg_end, N);

    // K2: scores = x @ wsc^T
    int waves = (N + 15) / 16;
    k_scores<<<(waves + 3) / 4, 256, 0, stream>>>(x, wsc, scores, N);

    // K3: segment softmax + weighted x accumulation
    k_softmax_xp<<<B, 256, 0, stream>>>(x, scores, seg_start, seg_end, xp);

    // K4: pooled[b, h*64+j] = sum_i xp[b,h,i] * W_v[h*64+j, i] + b_v[h*64+j]
    k_gemm_tn<<<dim3(B / 32, dh / 32, NHEAD), 256, 0, stream>>>(
        xp, NHEAD * 512, 512,
        W_in + (size_t)2 * D * D, D, dh * D,
        b_in + 2 * D, dh,
        pooled, D, dh, D);

    // K5: out = pooled @ W_out^T + b_out
    k_gemm_tn<<<dim3(B / 32, D / 32, 1), 256, 0, stream>>>(
        pooled, D, 0,
        W_out, D, 0,
        b_out, 0,
        out, D, 0, D);
}